// Round 16
// baseline (272.774 us; speedup 1.0000x reference)
//
#include <hip/hip_runtime.h>
#include <hip/hip_fp16.h>

typedef _Float16 f16x8  __attribute__((ext_vector_type(8)));
typedef _Float16 f16x4  __attribute__((ext_vector_type(4)));
typedef float    f32x4  __attribute__((ext_vector_type(4)));
typedef float    f32x16 __attribute__((ext_vector_type(16)));

#define BATCH 131072

// ---------------------------------------------------------------------------
// Kernel 1: synthesize weights in 32x32x16 MFMA FRAGMENT ORDER (per-layer
// blobs). Element e -> (pid, w, ni2, lane, j):
//   byte_off = ((pid*NW + w)*NI2 + ni2)*1024 + lane*16 + j*2
//   n = pid*PANEL + ni2*32 + (lane&31),  k = w*16 + (lane>>5)*8 + j
// Each wave wf load = ONE contiguous 1KB transaction.
// W[k][n] = tri(dist(p_i[k], p_{i+1}[n])) / sqrt(K).
// ---------------------------------------------------------------------------
__global__ void synth_weights_kernel(const float* __restrict__ p0, const float* __restrict__ p1,
                                     const float* __restrict__ p2, const float* __restrict__ p3,
                                     _Float16* __restrict__ blob0, _Float16* __restrict__ blob1,
                                     _Float16* __restrict__ blob2)
{
    const int idx = blockIdx.x * blockDim.x + threadIdx.x;   // 524288 total
    const float* A; const float* B; _Float16* Wt; float scl; int e, n, k;
    if (idx < 131072) {            // L1: K=256, NW=16, NI2=2, PANEL=64
        A = p0; B = p1; Wt = blob0; scl = 0.0625f; e = idx;
        const int j = e & 7, lane = (e >> 3) & 63, t = e >> 9;
        const int ni2 = t & 1, pw = t >> 1, w = pw & 15, pid = pw >> 4;
        n = pid * 64 + ni2 * 32 + (lane & 31);
        k = w * 16 + ((lane >> 5) << 3) + j;
    } else if (idx < 393216) {     // L2: K=512, NW=32, NI2=2, PANEL=64
        A = p1; B = p2; Wt = blob1; scl = 0.04419417382415922f; e = idx - 131072;
        const int j = e & 7, lane = (e >> 3) & 63, t = e >> 9;
        const int ni2 = t & 1, pw = t >> 1, w = pw & 31, pid = pw >> 5;
        n = pid * 64 + ni2 * 32 + (lane & 31);
        k = w * 16 + ((lane >> 5) << 3) + j;
    } else {                       // L3: K=512, NW=32, NI2=1, PANEL=32
        A = p2; B = p3; Wt = blob2; scl = 0.04419417382415922f; e = idx - 393216;
        const int j = e & 7, lane = (e >> 3) & 63, t = e >> 9;
        const int w = t & 31, pid = t >> 5;
        n = pid * 32 + (lane & 31);
        k = w * 16 + ((lane >> 5) << 3) + j;
    }
    float d2 = 0.f;
#pragma unroll
    for (int t = 0; t < 20; ++t) {
        float df = A[k * 20 + t] - B[n * 20 + t];
        d2 += df * df;
    }
    float d  = sqrtf(d2);
    float md = fmodf(d, 0.2f);                            // period 2P = 0.2, d >= 0
    float w  = 10.0f * (0.05f - fabsf(md - 0.1f)) * scl;  // AMP/P*(P-|m-P|-P/2)/sqrt(K)
    Wt[(size_t)e] = (_Float16)w;
}

// ---------------------------------------------------------------------------
// Fused MLP v16: R12's winning regime (512 thr, 64 rows, 64KB LDS, 4 w/SIMD)
// with 32x32x16 MFMA: per 16-k window only 4 MFMA + 2 wf + 2 xf loads ->
// half the issue slots/VALU of R12's 16x16 path, and the smaller fragment
// regs (wf 3-set = 24 < R12's 32) buy DEPTH-2 weight prefetch inside the
// 128-reg/wave budget (acc 64 AGPR + VGPR <= 64).
// frag layouts (32x32x16, R3-proven on HW):
//   A/B input: idx = lane&31, k = (lane>>5)*8 + j
//   D (swapped mfma(wf,xf)): m = lane&31, n = (reg&3) + 8*(reg>>2) + 4*(lane>>5)
// act slab [64][1024B], 16B-chunk swizzle c ^ (row&7), unchanged.
// ---------------------------------------------------------------------------
__device__ __forceinline__ f16x8 ld_act32(const char* act, int mi2, int rl32, int hi2, int w)
{
    const int row = mi2 * 32 + rl32;
    const int c   = w * 2 + hi2;
    return *(const f16x8*)(act + row * 1024 + ((c ^ (row & 7)) << 4));
}

template<int NW, int NI2, int MI2>
__device__ __forceinline__ void mm32(const char* act, const _Float16* __restrict__ blob,
                                     int lane, int pid, f32x16 (&acc)[NI2][MI2])
{
    const int rl32 = lane & 31;
    const int hi2  = lane >> 5;
    const char* wbase = (const char*)blob + ((size_t)pid * NW * NI2) * 1024 + lane * 16;

    f16x8 wf[3][NI2];                 // 3-set rotation = depth-2 weight prefetch
    f16x8 xfA[MI2], xfB[MI2];         // parity act sets

#pragma unroll
    for (int ni = 0; ni < NI2; ++ni) {
        wf[0][ni] = *(const f16x8*)(wbase + (0 * NI2 + ni) * 1024);
        wf[1][ni] = *(const f16x8*)(wbase + (1 * NI2 + ni) * 1024);
    }
#pragma unroll
    for (int mi = 0; mi < MI2; ++mi) xfA[mi] = ld_act32(act, mi, rl32, hi2, 0);

#pragma unroll
    for (int w = 0; w < NW; ++w) {
        if (w + 2 < NW) {
#pragma unroll
            for (int ni = 0; ni < NI2; ++ni)
                wf[(w + 2) % 3][ni] = *(const f16x8*)(wbase + ((w + 2) * NI2 + ni) * 1024);
        }
        if (w + 1 < NW) {
            if ((w & 1) == 0) {
#pragma unroll
                for (int mi = 0; mi < MI2; ++mi) xfB[mi] = ld_act32(act, mi, rl32, hi2, w + 1);
            } else {
#pragma unroll
                for (int mi = 0; mi < MI2; ++mi) xfA[mi] = ld_act32(act, mi, rl32, hi2, w + 1);
            }
        }
        __builtin_amdgcn_s_setprio(1);
#pragma unroll
        for (int mi = 0; mi < MI2; ++mi)
#pragma unroll
            for (int ni = 0; ni < NI2; ++ni)
                acc[ni][mi] = __builtin_amdgcn_mfma_f32_32x32x16_f16(
                    wf[w % 3][ni], ((w & 1) == 0 ? xfA : xfB)[mi], acc[ni][mi], 0, 0, 0);
        __builtin_amdgcn_s_setprio(0);
    }
}

// Write z (bias+relu) into act LDS [64][1024B]. Per lane/tile: 4 packs of 4
// consecutive n (8B f16x4), n0 = wn + g*8 + hi2*4, values reg 4g..4g+3.
template<int NI2, int MI2>
__device__ __forceinline__ void store_z32(char* act, const float* __restrict__ bias,
                                          int wc, int lane, f32x16 (&acc)[NI2][MI2])
{
    const int rl32 = lane & 31;
    const int hi2  = lane >> 5;
#pragma unroll
    for (int ni = 0; ni < NI2; ++ni) {
#pragma unroll
        for (int mi = 0; mi < MI2; ++mi) {
            const int m = mi * 32 + rl32;
#pragma unroll
            for (int g = 0; g < 4; ++g) {
                const int n0 = wc + ni * 32 + g * 8 + hi2 * 4;
                const float4 bv = *(const float4*)(bias + n0);
                f16x4 h;
                h[0] = (_Float16)fmaxf(acc[ni][mi][g * 4 + 0] + bv.x, 0.0f);
                h[1] = (_Float16)fmaxf(acc[ni][mi][g * 4 + 1] + bv.y, 0.0f);
                h[2] = (_Float16)fmaxf(acc[ni][mi][g * 4 + 2] + bv.z, 0.0f);
                h[3] = (_Float16)fmaxf(acc[ni][mi][g * 4 + 3] + bv.w, 0.0f);
                *(f16x4*)(act + m * 1024 + (((n0 >> 3) ^ (m & 7)) << 4) + (n0 & 7) * 2) = h;
            }
        }
    }
}

__global__ __launch_bounds__(512, 4)
void fused_mlp_kernel(const float* __restrict__ x,
                      const _Float16* __restrict__ blob0, const _Float16* __restrict__ blob1,
                      const _Float16* __restrict__ blob2,
                      const float* __restrict__ b1, const float* __restrict__ b2,
                      const float* __restrict__ b3,
                      float* __restrict__ out)
{
    extern __shared__ char act[];             // 64 KB act slab only
    const int tid  = threadIdx.x;
    const int lane = tid & 63;
    const int wid  = tid >> 6;                // 0..7 (n-panel id)
    const size_t m0 = (size_t)blockIdx.x * 64;

    // ---- stage x slab f32 -> f16 into act [64 rows][1024 B stride, 512 used]
#pragma unroll
    for (int it = 0; it < 4; ++it) {
        const int c   = it * 512 + tid;       // 2048 16B-chunks
        const int row = c >> 5;
        const int c8  = c & 31;
        const float* src = x + (m0 + row) * 256 + c8 * 8;
        const float4 v0 = *(const float4*)src;
        const float4 v1 = *(const float4*)(src + 4);
        f16x8 h;
        h[0] = (_Float16)v0.x; h[1] = (_Float16)v0.y; h[2] = (_Float16)v0.z; h[3] = (_Float16)v0.w;
        h[4] = (_Float16)v1.x; h[5] = (_Float16)v1.y; h[6] = (_Float16)v1.z; h[7] = (_Float16)v1.w;
        *(f16x8*)(act + row * 1024 + ((c8 ^ (row & 7)) << 4)) = h;
    }
    __syncthreads();

    const int wc = wid * 64;                  // wave's exclusive 64-n panel (L1/L2)

    // ---- layer 1: z1 = relu(x @ W0 + b1)   [64,256]@[256,512]
    {
        f32x16 acc[2][2] = {};
        mm32<16, 2, 2>(act, blob0, lane, wid, acc);
        __syncthreads();                      // all waves done reading x
        store_z32<2, 2>(act, b1, wc, lane, acc);
        __syncthreads();
    }

    // ---- layer 2: z2 = relu(z1 @ W1 + b2)  [64,512]@[512,512]  (in-place)
    {
        f32x16 acc[2][2] = {};
        mm32<32, 2, 2>(act, blob1, lane, wid, acc);
        __syncthreads();
        store_z32<2, 2>(act, b2, wc, lane, acc);
        __syncthreads();
    }

    // ---- layer 3: out = z2 @ W2 + b3       [64,512]@[512,256], direct f32
    //      g-inner: each out row receives its full 128B line in 4 consecutive
    //      store instructions (no partial-line RMW — R15-proven).
    {
        const int wc3 = wid * 32;             // wave's exclusive 32-n panel
        f32x16 acc[1][2] = {};
        mm32<32, 1, 2>(act, blob2, lane, wid, acc);

        const int rl32 = lane & 31;
        const int hi2  = lane >> 5;
#pragma unroll
        for (int mi = 0; mi < 2; ++mi) {
            const size_t m = m0 + mi * 32 + rl32;
#pragma unroll
            for (int g = 0; g < 4; ++g) {
                const int n0 = wc3 + g * 8 + hi2 * 4;
                const float4 bv = *(const float4*)(b3 + n0);
                f32x4 o;
                o[0] = acc[0][mi][g * 4 + 0] + bv.x;
                o[1] = acc[0][mi][g * 4 + 1] + bv.y;
                o[2] = acc[0][mi][g * 4 + 2] + bv.z;
                o[3] = acc[0][mi][g * 4 + 3] + bv.w;
                *(f32x4*)(out + m * 256 + n0) = o;
            }
        }
    }
}

// ---------------------------------------------------------------------------
// kernel_launch — ws: [blob0 256KB | blob1 512KB | blob2 256KB]
// ---------------------------------------------------------------------------
extern "C" void kernel_launch(void* const* d_in, const int* in_sizes, int n_in,
                              void* d_out, int out_size, void* d_ws, size_t ws_size,
                              hipStream_t stream)
{
    const float* x  = (const float*)d_in[0];
    const float* p0 = (const float*)d_in[1];
    const float* p1 = (const float*)d_in[2];
    const float* p2 = (const float*)d_in[3];
    const float* p3 = (const float*)d_in[4];
    const float* b1 = (const float*)d_in[5];
    const float* b2 = (const float*)d_in[6];
    const float* b3 = (const float*)d_in[7];

    char* ws = (char*)d_ws;
    _Float16* blob0 = (_Float16*)(ws);                    // 262144 B
    _Float16* blob1 = (_Float16*)(ws + 262144);           // 524288 B
    _Float16* blob2 = (_Float16*)(ws + 262144 + 524288);  // 262144 B

    synth_weights_kernel<<<2048, 256, 0, stream>>>(p0, p1, p2, p3, blob0, blob1, blob2);

    fused_mlp_kernel<<<BATCH / 64, 512, 65536, stream>>>(x, blob0, blob1, blob2,
                                                         b1, b2, b3, (float*)d_out);
}

// Round 17
// 243.521 us; speedup vs baseline: 1.1201x; 1.1201x over previous
//
#include <hip/hip_runtime.h>
#include <hip/hip_fp16.h>

typedef _Float16 f16x8  __attribute__((ext_vector_type(8)));
typedef _Float16 f16x4  __attribute__((ext_vector_type(4)));
typedef float    f32x4  __attribute__((ext_vector_type(4)));
typedef float    f32x16 __attribute__((ext_vector_type(16)));

#define BATCH 131072

// ---------------------------------------------------------------------------
// Kernel 1: synthesize weights in 32x32x16 fragment order, R11 geometry
// (8 n-panels of 64; window = 32 k = 2 k-halves). Element e -> frag coords:
//   f = h*NI2 + ni2 ; byte_off = (((pid*NW + w)*2 + h)*NI2 + ni2)*1024
//                                 + lane*16 + j*2
//   n = pid*PANEL + ni2*32 + (lane&31),  k = w*32 + h*16 + (lane>>5)*8 + j
// Each wave wf load = ONE contiguous 1KB transaction.
// W[k][n] = tri(dist(p_i[k], p_{i+1}[n])) / sqrt(K).
// ---------------------------------------------------------------------------
__global__ void synth_weights_kernel(const float* __restrict__ p0, const float* __restrict__ p1,
                                     const float* __restrict__ p2, const float* __restrict__ p3,
                                     _Float16* __restrict__ blob0, _Float16* __restrict__ blob1,
                                     _Float16* __restrict__ blob2)
{
    const int idx = blockIdx.x * blockDim.x + threadIdx.x;   // 524288 total
    const float* A; const float* B; _Float16* Wt; float scl; int e, n, k;
    if (idx < 131072) {            // L1: K=256, NW=8,  NF=4 (NI2=2), PANEL=64
        A = p0; B = p1; Wt = blob0; scl = 0.0625f; e = idx;
        const int j = e & 7, lane = (e >> 3) & 63, t = e >> 9;
        const int f = t & 3, pw = t >> 2, w = pw & 7, pid = pw >> 3;
        const int h = f >> 1, ni2 = f & 1;
        n = pid * 64 + ni2 * 32 + (lane & 31);
        k = w * 32 + h * 16 + ((lane >> 5) << 3) + j;
    } else if (idx < 393216) {     // L2: K=512, NW=16, NF=4 (NI2=2), PANEL=64
        A = p1; B = p2; Wt = blob1; scl = 0.04419417382415922f; e = idx - 131072;
        const int j = e & 7, lane = (e >> 3) & 63, t = e >> 9;
        const int f = t & 3, pw = t >> 2, w = pw & 15, pid = pw >> 4;
        const int h = f >> 1, ni2 = f & 1;
        n = pid * 64 + ni2 * 32 + (lane & 31);
        k = w * 32 + h * 16 + ((lane >> 5) << 3) + j;
    } else {                       // L3: K=512, NW=16, NF=2 (NI2=1), PANEL=32
        A = p2; B = p3; Wt = blob2; scl = 0.04419417382415922f; e = idx - 393216;
        const int j = e & 7, lane = (e >> 3) & 63, t = e >> 9;
        const int h = t & 1, pw = t >> 1, w = pw & 15, pid = pw >> 4;
        n = pid * 32 + (lane & 31);
        k = w * 32 + h * 16 + ((lane >> 5) << 3) + j;
    }
    float d2 = 0.f;
#pragma unroll
    for (int t = 0; t < 20; ++t) {
        float df = A[k * 20 + t] - B[n * 20 + t];
        d2 += df * df;
    }
    float d  = sqrtf(d2);
    float md = fmodf(d, 0.2f);                            // period 2P = 0.2, d >= 0
    float w  = 10.0f * (0.05f - fabsf(md - 0.1f)) * scl;  // AMP/P*(P-|m-P|-P/2)/sqrt(K)
    Wt[(size_t)e] = (_Float16)w;
}

// ---------------------------------------------------------------------------
// Fused MLP v17: R11 geometry (512 thr / 8 waves, 128 rows/block, 128 KB act
// LDS, __launch_bounds__(512,2) -> 256-reg budget) with 32x32x16 MFMA:
// per 32-k window 16 MFMA issues (vs R11's 32) at identical byte traffic,
// and wf gets DEPTH-2 prefetch (3-set rotation, 48 VGPR) with room to spare:
// acc 128 AGPR + wf 48 + xf 32 + addr ~20  ~= 228 <= 256. No spill (R16's
// failure was the 128-reg budget at 4 w/SIMD; this is the 256-reg regime).
// frag layouts (32x32x16, correctness-verified in R16):
//   A/B input: idx = lane&31, k = (lane>>5)*8 + j
//   D (swapped mfma(wf,xf)): m = lane&31, n = (reg&3) + 8*(reg>>2) + 4*(lane>>5)
// act slab [128][1024B], 16B-chunk swizzle c ^ (row&7), unchanged.
// ---------------------------------------------------------------------------
__device__ __forceinline__ f16x8 ld_act32(const char* act, int mi2, int rl32, int hi2,
                                          int w, int h)
{
    const int row = mi2 * 32 + rl32;
    const int c   = w * 4 + h * 2 + hi2;        // 16B-chunk index (k/8)
    return *(const f16x8*)(act + row * 1024 + ((c ^ (row & 7)) << 4));
}

template<int NW, int NI2, int MI2>
__device__ __forceinline__ void mm32(const char* act, const _Float16* __restrict__ blob,
                                     int lane, int pid, f32x16 (&acc)[NI2][MI2])
{
    const int rl32 = lane & 31;
    const int hi2  = lane >> 5;
    constexpr int NF = 2 * NI2;                 // frags per 32-k window
    const char* wbase = (const char*)blob + ((size_t)pid * NW * NF) * 1024 + lane * 16;

    f16x8 wf[3][NF];                            // 3-set rotation = depth-2 prefetch
#pragma unroll
    for (int f = 0; f < NF; ++f) {
        wf[0][f] = *(const f16x8*)(wbase + (0 * NF + f) * 1024);
        wf[1][f] = *(const f16x8*)(wbase + (1 * NF + f) * 1024);
    }

#pragma unroll
    for (int w = 0; w < NW; ++w) {
        // prefetch weights two windows ahead (compile-time slot)
        if (w + 2 < NW) {
#pragma unroll
            for (int f = 0; f < NF; ++f)
                wf[(w + 2) % 3][f] = *(const f16x8*)(wbase + ((w + 2) * NF + f) * 1024);
        }
        // acts for this window (single set; lgkm hides inside MFMA cluster)
        f16x8 xf[MI2][2];
#pragma unroll
        for (int mi = 0; mi < MI2; ++mi)
#pragma unroll
            for (int h = 0; h < 2; ++h)
                xf[mi][h] = ld_act32(act, mi, rl32, hi2, w, h);
        __builtin_amdgcn_s_setprio(1);
#pragma unroll
        for (int h = 0; h < 2; ++h)
#pragma unroll
            for (int ni = 0; ni < NI2; ++ni)
#pragma unroll
                for (int mi = 0; mi < MI2; ++mi)
                    acc[ni][mi] = __builtin_amdgcn_mfma_f32_32x32x16_f16(
                        wf[w % 3][h * NI2 + ni], xf[mi][h], acc[ni][mi], 0, 0, 0);
        __builtin_amdgcn_s_setprio(0);
    }
}

// Write z (bias+relu) into act LDS [128][1024B]; per (ni2,mi2,g): f16x4 pack
// of 4 consecutive n. Layout correctness-verified in R16.
template<int NI2, int MI2>
__device__ __forceinline__ void store_z32(char* act, const float* __restrict__ bias,
                                          int wc, int lane, f32x16 (&acc)[NI2][MI2])
{
    const int rl32 = lane & 31;
    const int hi2  = lane >> 5;
#pragma unroll
    for (int ni = 0; ni < NI2; ++ni) {
#pragma unroll
        for (int mi = 0; mi < MI2; ++mi) {
            const int m = mi * 32 + rl32;
#pragma unroll
            for (int g = 0; g < 4; ++g) {
                const int n0 = wc + ni * 32 + g * 8 + hi2 * 4;
                const float4 bv = *(const float4*)(bias + n0);
                f16x4 h;
                h[0] = (_Float16)fmaxf(acc[ni][mi][g * 4 + 0] + bv.x, 0.0f);
                h[1] = (_Float16)fmaxf(acc[ni][mi][g * 4 + 1] + bv.y, 0.0f);
                h[2] = (_Float16)fmaxf(acc[ni][mi][g * 4 + 2] + bv.z, 0.0f);
                h[3] = (_Float16)fmaxf(acc[ni][mi][g * 4 + 3] + bv.w, 0.0f);
                *(f16x4*)(act + m * 1024 + (((n0 >> 3) ^ (m & 7)) << 4) + (n0 & 7) * 2) = h;
            }
        }
    }
}

__global__ __launch_bounds__(512, 2)
void fused_mlp_kernel(const float* __restrict__ x,
                      const _Float16* __restrict__ blob0, const _Float16* __restrict__ blob1,
                      const _Float16* __restrict__ blob2,
                      const float* __restrict__ b1, const float* __restrict__ b2,
                      const float* __restrict__ b3,
                      float* __restrict__ out)
{
    extern __shared__ char act[];             // 128 KB act slab only
    const int tid  = threadIdx.x;
    const int lane = tid & 63;
    const int wid  = tid >> 6;                // 0..7 (n-panel id)
    const size_t m0 = (size_t)blockIdx.x * 128;

    // ---- stage x slab f32 -> f16 into act [128 rows][1024 B stride, 512 used]
#pragma unroll
    for (int it = 0; it < 8; ++it) {
        const int c   = it * 512 + tid;       // 4096 16B-chunks
        const int row = c >> 5;
        const int c8  = c & 31;
        const float* src = x + (m0 + row) * 256 + c8 * 8;
        const float4 v0 = *(const float4*)src;
        const float4 v1 = *(const float4*)(src + 4);
        f16x8 h;
        h[0] = (_Float16)v0.x; h[1] = (_Float16)v0.y; h[2] = (_Float16)v0.z; h[3] = (_Float16)v0.w;
        h[4] = (_Float16)v1.x; h[5] = (_Float16)v1.y; h[6] = (_Float16)v1.z; h[7] = (_Float16)v1.w;
        *(f16x8*)(act + row * 1024 + ((c8 ^ (row & 7)) << 4)) = h;
    }
    __syncthreads();

    const int wc = wid * 64;                  // wave's exclusive 64-n panel (L1/L2)

    // ---- layer 1: z1 = relu(x @ W0 + b1)   [128,256]@[256,512]
    {
        f32x16 acc[2][4] = {};
        mm32<8, 2, 4>(act, blob0, lane, wid, acc);
        __syncthreads();                      // all waves done reading x
        store_z32<2, 4>(act, b1, wc, lane, acc);
        __syncthreads();
    }

    // ---- layer 2: z2 = relu(z1 @ W1 + b2)  [128,512]@[512,512]  (in-place)
    {
        f32x16 acc[2][4] = {};
        mm32<16, 2, 4>(act, blob1, lane, wid, acc);
        __syncthreads();
        store_z32<2, 4>(act, b2, wc, lane, acc);
        __syncthreads();
    }

    // ---- layer 3: out = z2 @ W2 + b3       [128,512]@[512,256], direct f32
    //      g-inner: each out row's 128B line filled by 4 consecutive stores.
    {
        const int wc3 = wid * 32;             // wave's exclusive 32-n panel
        f32x16 acc[1][4] = {};
        mm32<16, 1, 4>(act, blob2, lane, wid, acc);

        const int rl32 = lane & 31;
        const int hi2  = lane >> 5;
#pragma unroll
        for (int mi = 0; mi < 4; ++mi) {
            const size_t m = m0 + mi * 32 + rl32;
#pragma unroll
            for (int g = 0; g < 4; ++g) {
                const int n0 = wc3 + g * 8 + hi2 * 4;
                const float4 bv = *(const float4*)(b3 + n0);
                f32x4 o;
                o[0] = acc[0][mi][g * 4 + 0] + bv.x;
                o[1] = acc[0][mi][g * 4 + 1] + bv.y;
                o[2] = acc[0][mi][g * 4 + 2] + bv.z;
                o[3] = acc[0][mi][g * 4 + 3] + bv.w;
                *(f32x4*)(out + m * 256 + n0) = o;
            }
        }
    }
}

// ---------------------------------------------------------------------------
// kernel_launch — ws: [blob0 256KB | blob1 512KB | blob2 256KB]
// ---------------------------------------------------------------------------
extern "C" void kernel_launch(void* const* d_in, const int* in_sizes, int n_in,
                              void* d_out, int out_size, void* d_ws, size_t ws_size,
                              hipStream_t stream)
{
    const float* x  = (const float*)d_in[0];
    const float* p0 = (const float*)d_in[1];
    const float* p1 = (const float*)d_in[2];
    const float* p2 = (const float*)d_in[3];
    const float* p3 = (const float*)d_in[4];
    const float* b1 = (const float*)d_in[5];
    const float* b2 = (const float*)d_in[6];
    const float* b3 = (const float*)d_in[7];

    char* ws = (char*)d_ws;
    _Float16* blob0 = (_Float16*)(ws);                    // 262144 B
    _Float16* blob1 = (_Float16*)(ws + 262144);           // 524288 B
    _Float16* blob2 = (_Float16*)(ws + 262144 + 524288);  // 262144 B

    synth_weights_kernel<<<2048, 256, 0, stream>>>(p0, p1, p2, p3, blob0, blob1, blob2);

    fused_mlp_kernel<<<BATCH / 128, 512, 131072, stream>>>(x, blob0, blob1, blob2,
                                                           b1, b2, b3, (float*)d_out);
}

// Round 18
// 155.680 us; speedup vs baseline: 1.7521x; 1.5642x over previous
//
#include <hip/hip_runtime.h>
#include <hip/hip_fp16.h>

typedef _Float16 f16x8 __attribute__((ext_vector_type(8)));
typedef _Float16 f16x4 __attribute__((ext_vector_type(4)));
typedef float    f32x4 __attribute__((ext_vector_type(4)));

#define BATCH 131072

// ---------------------------------------------------------------------------
// Kernel 1: synthesize weights in 16x16x32 MFMA fragment order, 4-panel
// geometry (L1/L2: 4 panels x 128 n, NI=8; L3: 4 panels x 64 n, NI=4).
//   byte_off = ((pid*NW + w)*NI + ni)*1024 + lane*16 + j*2
//   n = pid*PANEL + ni*16 + (lane&15),  k = w*32 + (lane>>4)*8 + j
// Each wave wf load = ONE contiguous 1KB transaction.
// W[k][n] = tri(dist(p_i[k], p_{i+1}[n])) / sqrt(K).
// ---------------------------------------------------------------------------
__global__ void synth_weights_kernel(const float* __restrict__ p0, const float* __restrict__ p1,
                                     const float* __restrict__ p2, const float* __restrict__ p3,
                                     _Float16* __restrict__ blob0, _Float16* __restrict__ blob1,
                                     _Float16* __restrict__ blob2)
{
    const int idx = blockIdx.x * blockDim.x + threadIdx.x;   // 524288 total
    const float* A; const float* B; _Float16* Wt; float scl; int e, n, k;
    if (idx < 131072) {            // L1: K=256, NW=8,  NI=8, PANEL=128
        A = p0; B = p1; Wt = blob0; scl = 0.0625f; e = idx;
        const int j = e & 7, lane = (e >> 3) & 63, t = e >> 9;
        const int ni = t & 7, pw = t >> 3, w = pw & 7, pid = pw >> 3;
        n = pid * 128 + ni * 16 + (lane & 15);
        k = w * 32 + ((lane >> 4) << 3) + j;
    } else if (idx < 393216) {     // L2: K=512, NW=16, NI=8, PANEL=128
        A = p1; B = p2; Wt = blob1; scl = 0.04419417382415922f; e = idx - 131072;
        const int j = e & 7, lane = (e >> 3) & 63, t = e >> 9;
        const int ni = t & 7, pw = t >> 3, w = pw & 15, pid = pw >> 4;
        n = pid * 128 + ni * 16 + (lane & 15);
        k = w * 32 + ((lane >> 4) << 3) + j;
    } else {                       // L3: K=512, NW=16, NI=4, PANEL=64
        A = p2; B = p3; Wt = blob2; scl = 0.04419417382415922f; e = idx - 393216;
        const int j = e & 7, lane = (e >> 3) & 63, t = e >> 9;
        const int ni = t & 3, pw = t >> 2, w = pw & 15, pid = pw >> 4;
        n = pid * 64 + ni * 16 + (lane & 15);
        k = w * 32 + ((lane >> 4) << 3) + j;
    }
    float d2 = 0.f;
#pragma unroll
    for (int t = 0; t < 20; ++t) {
        float df = A[k * 20 + t] - B[n * 20 + t];
        d2 += df * df;
    }
    float d  = sqrtf(d2);
    float md = fmodf(d, 0.2f);                            // period 2P = 0.2, d >= 0
    float w  = 10.0f * (0.05f - fabsf(md - 0.1f)) * scl;  // AMP/P*(P-|m-P|-P/2)/sqrt(K)
    Wt[(size_t)e] = (_Float16)w;
}

// ---------------------------------------------------------------------------
// Fused MLP v18: CROSS-BLOCK OVERLAP regime. 256 threads (4 waves), 64
// rows/block, 64 KB LDS -> TWO independent blocks per CU at 2 w/SIMD
// (256-reg/wave budget intact). Block A's layer-boundary store_z/barrier/
// epilogue overlaps block B's k-loop -- R11's single-block drain exposed
// all of that serially. Per-wave tile 64m x 128n (NI=8, MI=4): acc 128 AGPR
// + wf 2x8 frags (64 VGPR) + xf 16 + addr ~= 100 VGPR <= 128 cap.
//   - wf: coalesced fragment-ordered blob loads, depth-1 double-buffer,
//     ph-staggered; xf single-set (R12-proven best at this depth).
//   - NO barriers in k-loop; barriers only around store_z.
// frag layouts (16x16x32, HW-verified R1-R15):
//   A/B input: index = lane&15, k = (lane>>4)*8 + j
//   D (swapped: mfma(wf, xf)): m = lane&15, n = (lane>>4)*4 + q (+16*ni)
// ---------------------------------------------------------------------------
__device__ __forceinline__ f16x8 ld_act(const char* act, int mi, int rl, int hi, int w)
{
    const int row = mi * 16 + rl;
    const int c   = w * 4 + hi;
    return *(const f16x8*)(act + row * 1024 + ((c ^ (row & 7)) << 4));
}

template<int NW, int NI, int MI>
__device__ __forceinline__ void mm_reg(const char* act, const _Float16* __restrict__ blob,
                                       int lane, int pid, f32x4 (&acc)[NI][MI])
{
    const int rl = lane & 15;
    const int hi = lane >> 4;
    const int ph = (pid * (NW / 4)) & (NW - 1);   // per-wave start window (4 waves)

    const char* wbase = (const char*)blob + ((size_t)pid * NW * NI) * 1024 + lane * 16;

    f16x8 wfA[NI], wfB[NI];
#pragma unroll
    for (int ni = 0; ni < NI; ++ni)
        wfA[ni] = *(const f16x8*)(wbase + (ph * NI + ni) * 1024);

#pragma unroll 1
    for (int w0 = 0; w0 < NW; w0 += 2) {
        const int wA = (w0 + ph) & (NW - 1);
        const int wB = (w0 + 1 + ph) & (NW - 1);
#pragma unroll
        for (int ni = 0; ni < NI; ++ni)
            wfB[ni] = *(const f16x8*)(wbase + (wB * NI + ni) * 1024);
        {
            f16x8 xf[MI];
#pragma unroll
            for (int mi = 0; mi < MI; ++mi) xf[mi] = ld_act(act, mi, rl, hi, wA);
            __builtin_amdgcn_s_setprio(1);
#pragma unroll
            for (int mi = 0; mi < MI; ++mi)
#pragma unroll
                for (int ni = 0; ni < NI; ++ni)
                    acc[ni][mi] = __builtin_amdgcn_mfma_f32_16x16x32_f16(wfA[ni], xf[mi], acc[ni][mi], 0, 0, 0);
            __builtin_amdgcn_s_setprio(0);
        }
        if (w0 + 2 < NW) {
            const int wC = (w0 + 2 + ph) & (NW - 1);
#pragma unroll
            for (int ni = 0; ni < NI; ++ni)
                wfA[ni] = *(const f16x8*)(wbase + (wC * NI + ni) * 1024);
        }
        {
            f16x8 xf[MI];
#pragma unroll
            for (int mi = 0; mi < MI; ++mi) xf[mi] = ld_act(act, mi, rl, hi, wB);
            __builtin_amdgcn_s_setprio(1);
#pragma unroll
            for (int mi = 0; mi < MI; ++mi)
#pragma unroll
                for (int ni = 0; ni < NI; ++ni)
                    acc[ni][mi] = __builtin_amdgcn_mfma_f32_16x16x32_f16(wfB[ni], xf[mi], acc[ni][mi], 0, 0, 0);
            __builtin_amdgcn_s_setprio(0);
        }
    }
}

// Write z (bias+relu) into act LDS [64][1024B] as 8B packs of 4 consecutive n.
template<int NI, int MI>
__device__ __forceinline__ void store_z(char* act, const float* __restrict__ bias,
                                        int wc, int lane, f32x4 (&acc)[NI][MI])
{
    const int rl = lane & 15;
    const int hi = lane >> 4;
#pragma unroll
    for (int ni = 0; ni < NI; ++ni) {
        const int n0 = wc + ni * 16 + hi * 4;
        const float4 bv = *(const float4*)(bias + n0);
#pragma unroll
        for (int mi = 0; mi < MI; ++mi) {
            const int m = mi * 16 + rl;
            f16x4 h;
            h[0] = (_Float16)fmaxf(acc[ni][mi][0] + bv.x, 0.0f);
            h[1] = (_Float16)fmaxf(acc[ni][mi][1] + bv.y, 0.0f);
            h[2] = (_Float16)fmaxf(acc[ni][mi][2] + bv.z, 0.0f);
            h[3] = (_Float16)fmaxf(acc[ni][mi][3] + bv.w, 0.0f);
            *(f16x4*)(act + m * 1024 + (((n0 >> 3) ^ (m & 7)) << 4) + (n0 & 7) * 2) = h;
        }
    }
}

__global__ __launch_bounds__(256, 2)
void fused_mlp_kernel(const float* __restrict__ x,
                      const _Float16* __restrict__ blob0, const _Float16* __restrict__ blob1,
                      const _Float16* __restrict__ blob2,
                      const float* __restrict__ b1, const float* __restrict__ b2,
                      const float* __restrict__ b3,
                      float* __restrict__ out)
{
    extern __shared__ char act[];             // 64 KB act slab
    const int tid  = threadIdx.x;
    const int lane = tid & 63;
    const int wid  = tid >> 6;                // 0..3 (n-panel id)
    const size_t m0 = (size_t)blockIdx.x * 64;

    // ---- stage x slab f32 -> f16 into act [64 rows][1024 B stride, 512 used]
#pragma unroll
    for (int it = 0; it < 8; ++it) {
        const int c   = it * 256 + tid;       // 2048 16B-chunks
        const int row = c >> 5;
        const int c8  = c & 31;
        const float* src = x + (m0 + row) * 256 + c8 * 8;
        const float4 v0 = *(const float4*)src;
        const float4 v1 = *(const float4*)(src + 4);
        f16x8 h;
        h[0] = (_Float16)v0.x; h[1] = (_Float16)v0.y; h[2] = (_Float16)v0.z; h[3] = (_Float16)v0.w;
        h[4] = (_Float16)v1.x; h[5] = (_Float16)v1.y; h[6] = (_Float16)v1.z; h[7] = (_Float16)v1.w;
        *(f16x8*)(act + row * 1024 + ((c8 ^ (row & 7)) << 4)) = h;
    }
    __syncthreads();

    const int wc = wid * 128;                 // wave's exclusive 128-n panel (L1/L2)

    // ---- layer 1: z1 = relu(x @ W0 + b1)   [64,256]@[256,512]
    {
        f32x4 acc[8][4] = {};
        mm_reg<8, 8, 4>(act, blob0, lane, wid, acc);
        __syncthreads();                      // all waves done reading x
        store_z<8, 4>(act, b1, wc, lane, acc);
        __syncthreads();
    }

    // ---- layer 2: z2 = relu(z1 @ W1 + b2)  [64,512]@[512,512]  (in-place)
    {
        f32x4 acc[8][4] = {};
        mm_reg<16, 8, 4>(act, blob1, lane, wid, acc);
        __syncthreads();
        store_z<8, 4>(act, b2, wc, lane, acc);
        __syncthreads();
    }

    // ---- layer 3: out = z2 @ W2 + b3       [64,512]@[512,256], direct f32
    //      mi-outer / ni-inner: full 128B out-lines back-to-back (R15-proven).
    {
        const int wc3 = wid * 64;             // wave's exclusive 64-n panel
        f32x4 acc[4][4] = {};
        mm_reg<16, 4, 4>(act, blob2, lane, wid, acc);

        const int rl = lane & 15;
        const int hi = lane >> 4;
#pragma unroll
        for (int mi = 0; mi < 4; ++mi) {
            const size_t m = m0 + mi * 16 + rl;
#pragma unroll
            for (int ni = 0; ni < 4; ++ni) {
                const int n0 = wc3 + ni * 16 + hi * 4;
                const float4 bv = *(const float4*)(b3 + n0);
                f32x4 o;
                o[0] = acc[ni][mi][0] + bv.x;
                o[1] = acc[ni][mi][1] + bv.y;
                o[2] = acc[ni][mi][2] + bv.z;
                o[3] = acc[ni][mi][3] + bv.w;
                *(f32x4*)(out + m * 256 + n0) = o;
            }
        }
    }
}

// ---------------------------------------------------------------------------
// kernel_launch — ws: [blob0 256KB | blob1 512KB | blob2 256KB]
// ---------------------------------------------------------------------------
extern "C" void kernel_launch(void* const* d_in, const int* in_sizes, int n_in,
                              void* d_out, int out_size, void* d_ws, size_t ws_size,
                              hipStream_t stream)
{
    const float* x  = (const float*)d_in[0];
    const float* p0 = (const float*)d_in[1];
    const float* p1 = (const float*)d_in[2];
    const float* p2 = (const float*)d_in[3];
    const float* p3 = (const float*)d_in[4];
    const float* b1 = (const float*)d_in[5];
    const float* b2 = (const float*)d_in[6];
    const float* b3 = (const float*)d_in[7];

    char* ws = (char*)d_ws;
    _Float16* blob0 = (_Float16*)(ws);                    // 262144 B
    _Float16* blob1 = (_Float16*)(ws + 262144);           // 524288 B
    _Float16* blob2 = (_Float16*)(ws + 262144 + 524288);  // 262144 B

    synth_weights_kernel<<<2048, 256, 0, stream>>>(p0, p1, p2, p3, blob0, blob1, blob2);

    fused_mlp_kernel<<<BATCH / 64, 256, 65536, stream>>>(x, blob0, blob1, blob2,
                                                         b1, b2, b3, (float*)d_out);
}